// Round 5
// baseline (139.866 us; speedup 1.0000x reference)
//
#include <hip/hip_runtime.h>
#include <math.h>

// Problem constants (fixed by the reference setup_inputs)
#define NIMG   64
#define CDIM   64
#define HWPX   4096
#define PARTS  8                 // 8 parts -> 17 MB partials (ws-proven; 16 parts over ws -> atomic fallback!)
#define KCL    128
#define PIXPART (HWPX / PARTS)   // 512 pixels per block
#define TL     32                // pixels per chunk
#define NCHUNK (PIXPART / TL)    // 16
#define SHIFT  10.0f             // softmax shift folded into bias
#define RSQRT128 0.08838834764831845f

// LDS strides in shorts (multiples of 8 so b128 stays 16B-aligned)
#define XP_S 72    // xp planes [32 p][64 c]
#define XC_S 40    // xc planes [64 c][32 p]
#define PH_S 40    // ph planes [128 k][32 p]

typedef __attribute__((ext_vector_type(8))) short short8; // 8 bf16
typedef __attribute__((ext_vector_type(4))) short short4v;
typedef __attribute__((ext_vector_type(4))) float f32x4;  // MFMA C/D

#define MFMA(a, b, c) __builtin_amdgcn_mfma_f32_16x16x32_bf16((a), (b), (c), 0, 0, 0)

// truncation split: hi = top16 bits, lo = bf16(f - hi). Dropped lo*lo term
// ~2^-16 relative -- well inside the 4.3e-4 output threshold.
__device__ __forceinline__ void tsplit(float f, short& hs, short& ls) {
    unsigned u = __builtin_bit_cast(unsigned, f);
    hs = (short)(u >> 16);
    float hf = __builtin_bit_cast(float, u & 0xffff0000u);
    ls = (short)(__builtin_bit_cast(unsigned, f - hf) >> 16);
}

// ---------------------------------------------------------------------------
// Kernel 1: raw-x planes -> mm1 (W@X) -> in-register softmax -> mm2 (P'@X^T)
// grid = NIMG*PARTS = 512 blocks of 512 threads (8 waves; wave w owns the
// 16-k tile [16w,16w+16)). 2 blocks/CU x 8 waves = 16 waves/CU (2x round 4).
// ---------------------------------------------------------------------------
__global__ __launch_bounds__(512, 4)
void netvlad_main(const float* __restrict__ x,       // [N][C][HW]
                  const float* __restrict__ conv_w,  // [K][C]
                  const float* __restrict__ conv_b,  // [K]
                  float* __restrict__ vout,          // partials or atomic acc
                  float* __restrict__ asout,
                  int use_atomic)
{
    __shared__ __align__(16) short xp_hi[TL * XP_S],  xp_lo[TL * XP_S];   // 9 KB
    __shared__ __align__(16) short xc_hi[CDIM * XC_S], xc_lo[CDIM * XC_S];// 10 KB
    __shared__ __align__(16) short ph_hi[KCL * PH_S],  ph_lo[KCL * PH_S]; // 20 KB
    __shared__ __align__(16) float redA[TL * 8];      // ssq partials [p][wave]
    __shared__ __align__(16) float sumP[TL * 8];      // exp-sum partials [p][wave]

    const int t   = threadIdx.x;
    const int w   = t >> 6;             // wave 0..7 -> k-tile w
    const int l   = t & 63;
    const int l15 = l & 15, l4 = l >> 4;
    const int n    = blockIdx.x >> 3;
    const int part = blockIdx.x & 7;
    const int p_s  = t & 31;            // staging pixel
    const int sg   = t >> 5;            // staging c-group (4 c's), 0..15

    // ---- W fragments in registers (once): A[m=k][kdim=c], k-tile w --------
    short8 wh[2], wl[2];
    {
        const int krow = w * 16 + l15;
        #pragma unroll
        for (int ks = 0; ks < 2; ++ks) {
            const float4* wp = (const float4*)(conv_w + krow * CDIM + ks * 32 + l4 * 8);
            float4 wa = wp[0], wb = wp[1];
            float wv[8] = {wa.x, wa.y, wa.z, wa.w, wb.x, wb.y, wb.z, wb.w};
            #pragma unroll
            for (int j = 0; j < 8; ++j) {
                short hs, ls; tsplit(wv[j], hs, ls);
                wh[ks][j] = hs; wl[ks][j] = ls;
            }
        }
    }
    // bias per D-row (k = w*16 + l4*4 + i), pre-shifted
    float cbr[4];
    #pragma unroll
    for (int i = 0; i < 4; ++i)
        cbr[i] = conv_b[w * 16 + l4 * 4 + i] - SHIFT;

    f32x4 acc2[4];                      // V tiles [ct] (rows = wave's 16 k)
    #pragma unroll
    for (int b = 0; b < 4; ++b) acc2[b] = (f32x4)0.0f;
    float asr[4] = {0.f, 0.f, 0.f, 0.f};

    const float* xbase = x + (size_t)n * CDIM * HWPX + part * PIXPART;

    // preload chunk 0: 4 c's per thread
    float xv[4];
    #pragma unroll
    for (int j = 0; j < 4; ++j)
        xv[j] = xbase[(sg * 4 + j) * HWPX + p_s];

    for (int ch = 0; ch < NCHUNK; ++ch) {
        // ---- stage: ssq partial + raw-x split planes ----------------------
        float ssq = 0.f;
        #pragma unroll
        for (int j = 0; j < 4; ++j) ssq += xv[j] * xv[j];
        ssq += __shfl_xor(ssq, 32);              // combine the wave's 2 sg's
        if (l < 32) redA[p_s * 8 + w] = ssq;

        {
            short4v vh, vl;
            #pragma unroll
            for (int j = 0; j < 4; ++j) {
                short hs, ls; tsplit(xv[j], hs, ls);
                vh[j] = hs; vl[j] = ls;
                xc_hi[(sg * 4 + j) * XC_S + p_s] = hs;
                xc_lo[(sg * 4 + j) * XC_S + p_s] = ls;
            }
            *(short4v*)&xp_hi[p_s * XP_S + sg * 4] = vh;
            *(short4v*)&xp_lo[p_s * XP_S + sg * 4] = vl;
        }
        __syncthreads();                                  // bar: stage done

        // prefetch next chunk while mm1/softmax/mm2 run
        if (ch + 1 < NCHUNK) {
            #pragma unroll
            for (int j = 0; j < 4; ++j)
                xv[j] = xbase[(sg * 4 + j) * HWPX + (ch + 1) * TL + p_s];
        }

        // ---- mm1: a1[pt] = W @ Xraw for wave's 16 k rows ------------------
        f32x4 a1[2];
        a1[0] = (f32x4)0.0f; a1[1] = (f32x4)0.0f;
        #pragma unroll
        for (int ks = 0; ks < 2; ++ks) {
            #pragma unroll
            for (int pt = 0; pt < 2; ++pt) {
                short8 bh = *(short8*)&xp_hi[(pt * 16 + l15) * XP_S + ks * 32 + l4 * 8];
                short8 bl = *(short8*)&xp_lo[(pt * 16 + l15) * XP_S + ks * 32 + l4 * 8];
                a1[pt] = MFMA(wh[ks], bh, a1[pt]);
                a1[pt] = MFMA(wh[ks], bl, a1[pt]);
                a1[pt] = MFMA(wl[ks], bh, a1[pt]);
            }
        }

        // ---- per-column 1/||x||: sum 8 ssq partials -----------------------
        float rn[2];
        #pragma unroll
        for (int pt = 0; pt < 2; ++pt) {
            const float4* r = (const float4*)&redA[(pt * 16 + l15) * 8];
            float4 r0 = r[0], r1 = r[1];
            rn[pt] = 1.0f / fmaxf(sqrtf((r0.x + r0.y) + (r0.z + r0.w)
                                      + (r1.x + r1.y) + (r1.z + r1.w)), 1e-12f);
        }

        // ---- in-register softmax over k (no max pass; bias pre-shifted) ---
        float e[2][4], sp[2] = {0.f, 0.f};
        #pragma unroll
        for (int pt = 0; pt < 2; ++pt)
            #pragma unroll
            for (int i = 0; i < 4; ++i) {
                float ev = __expf(fmaf(a1[pt][i], rn[pt], cbr[i]));
                e[pt][i] = ev;
                sp[pt] += ev;
            }
        #pragma unroll
        for (int pt = 0; pt < 2; ++pt) {
            sp[pt] += __shfl_xor(sp[pt], 16);
            sp[pt] += __shfl_xor(sp[pt], 32);    // sum over wave's 16 k rows
        }
        if (l4 == 0) {                            // lanes 0..15
            sumP[l15 * 8 + w]        = sp[0];
            sumP[(16 + l15) * 8 + w] = sp[1];
        }
        __syncthreads();                                  // bar: sumP done

        float rden[2], rdn2[2];
        #pragma unroll
        for (int pt = 0; pt < 2; ++pt) {
            const float4* r = (const float4*)&sumP[(pt * 16 + l15) * 8];
            float4 r0 = r[0], r1 = r[1];
            float den = (r0.x + r0.y) + (r0.z + r0.w)
                      + (r1.x + r1.y) + (r1.z + r1.w);
            rden[pt] = 1.0f / den;
            rdn2[pt] = rden[pt] * rn[pt];          // fold 1/||x|| into P'
        }

        // ---- P' = P * rn, split to planes; asr += P ----------------------
        #pragma unroll
        for (int i = 0; i < 4; ++i) {
            const int row = w * 16 + l4 * 4 + i;
            #pragma unroll
            for (int pt = 0; pt < 2; ++pt) {
                float ev = e[pt][i];
                asr[i] = fmaf(ev, rden[pt], asr[i]);
                float Pn = ev * rdn2[pt];
                short hs, ls; tsplit(Pn, hs, ls);
                ph_hi[row * PH_S + pt * 16 + l15] = hs;
                ph_lo[row * PH_S + pt * 16 + l15] = ls;
            }
        }
        __syncthreads();                                  // bar: P planes done

        // ---- mm2: V[k][c] += P' @ Xraw^T (wave's 16 k rows) --------------
        {
            short8 ah = *(short8*)&ph_hi[(w * 16 + l15) * PH_S + l4 * 8];
            short8 al = *(short8*)&ph_lo[(w * 16 + l15) * PH_S + l4 * 8];
            #pragma unroll
            for (int ct = 0; ct < 4; ++ct) {
                short8 xh2 = *(short8*)&xc_hi[(ct * 16 + l15) * XC_S + l4 * 8];
                short8 xl2 = *(short8*)&xc_lo[(ct * 16 + l15) * XC_S + l4 * 8];
                acc2[ct] = MFMA(ah, xh2, acc2[ct]);
                acc2[ct] = MFMA(ah, xl2, acc2[ct]);
                acc2[ct] = MFMA(al, xh2, acc2[ct]);
            }
        }
        __syncthreads();                                  // bar: chunk end
    }

    // ---- V write (coalesced: lanes l15 -> consecutive c) ------------------
    float* vg = use_atomic ? vout + (size_t)n * KCL * CDIM
                           : vout + (size_t)(n * PARTS + part) * KCL * CDIM;
    #pragma unroll
    for (int ct = 0; ct < 4; ++ct)
        #pragma unroll
        for (int i = 0; i < 4; ++i) {
            const int row = w * 16 + l4 * 4 + i;
            const int col = ct * 16 + l15;
            if (use_atomic) atomicAdd(&vg[row * CDIM + col], acc2[ct][i]);
            else            vg[row * CDIM + col] = acc2[ct][i];
        }

    // ---- asum: reduce over l15 lanes, lane0-of-16 writes ------------------
    #pragma unroll
    for (int i = 0; i < 4; ++i) {
        float v = asr[i];
        v += __shfl_xor(v, 1); v += __shfl_xor(v, 2);
        v += __shfl_xor(v, 4); v += __shfl_xor(v, 8);
        if (l15 == 0) {
            const int row = w * 16 + l4 * 4 + i;
            if (use_atomic) atomicAdd(&asout[n * KCL + row], v);
            else            asout[(n * PARTS + part) * KCL + row] = v;
        }
    }
}

// ---------------------------------------------------------------------------
// Kernel 2: sum partials; vlad = V - asum*cent; intra-norm; global norm.
// Global norm: after intra-norm every row has unit L2 norm, so the global
// denominator is sqrt(K)=sqrt(128) exactly (up to fp) -- rows are independent.
// grid = NIMG*8 blocks x 256 threads; thread -> (k, 4 c's). Fully parallel.
// ---------------------------------------------------------------------------
__global__ __launch_bounds__(256)
void netvlad_finalize(const float* __restrict__ vpart,   // [N][nparts][K][C]
                      const float* __restrict__ aspart,  // [N][nparts][K]
                      const float* __restrict__ cent,    // [K][C]
                      float* __restrict__ out,           // [N][K*C]
                      int nparts)
{
    const int t = threadIdx.x;
    const int n  = blockIdx.x >> 3;
    const int kg = blockIdx.x & 7;
    const int k  = kg * 16 + (t >> 4);
    const int c0 = (t & 15) * 4;

    float vsum[4] = {0.f, 0.f, 0.f, 0.f};
    float av = 0.f;
    for (int pt = 0; pt < nparts; ++pt) {
        const float* vg = vpart + (((size_t)n * nparts + pt) * KCL + k) * CDIM + c0;
        float4 a = *(const float4*)vg;
        vsum[0] += a.x; vsum[1] += a.y; vsum[2] += a.z; vsum[3] += a.w;
        av += aspart[(n * nparts + pt) * KCL + k];
    }

    float4 cq = *(const float4*)(cent + k * CDIM + c0);
    float cc[4] = {cq.x, cq.y, cq.z, cq.w};
    float ss = 0.f;
    #pragma unroll
    for (int j = 0; j < 4; ++j) {
        vsum[j] -= av * cc[j];
        ss += vsum[j] * vsum[j];
    }
    // row sumsq over the 16 lanes covering this k (lanes differ only in t&15)
    ss += __shfl_xor(ss, 1); ss += __shfl_xor(ss, 2);
    ss += __shfl_xor(ss, 4); ss += __shfl_xor(ss, 8);
    const float s = (1.0f / fmaxf(sqrtf(ss), 1e-12f)) * RSQRT128;

    float4 o;
    o.x = vsum[0] * s; o.y = vsum[1] * s; o.z = vsum[2] * s; o.w = vsum[3] * s;
    *(float4*)(out + (size_t)n * KCL * CDIM + k * CDIM + c0) = o;
}

// ---------------------------------------------------------------------------
extern "C" void kernel_launch(void* const* d_in, const int* in_sizes, int n_in,
                              void* d_out, int out_size, void* d_ws, size_t ws_size,
                              hipStream_t stream) {
    const float* x     = (const float*)d_in[0];   // [64,64,64,64]
    const float* cent  = (const float*)d_in[1];   // [128,64]
    const float* convw = (const float*)d_in[2];   // [128,64]
    const float* convb = (const float*)d_in[3];   // [128]
    float* out = (float*)d_out;

    const size_t needP = (size_t)NIMG * PARTS * (KCL * CDIM + KCL) * sizeof(float);
    int nparts, use_atomic;
    if (ws_size >= needP) { nparts = PARTS; use_atomic = 0; }
    else                  { nparts = 1;     use_atomic = 1; }

    float* vws  = (float*)d_ws;                               // [N][nparts][K][C]
    float* asws = vws + (size_t)NIMG * nparts * KCL * CDIM;   // [N][nparts][K]
    if (use_atomic) {
        const size_t zb = (size_t)NIMG * (KCL * CDIM + KCL) * sizeof(float);
        hipMemsetAsync(d_ws, 0, zb, stream);
    }

    netvlad_main<<<dim3(NIMG * PARTS), dim3(512), 0, stream>>>(x, convw, convb, vws, asws, use_atomic);
    netvlad_finalize<<<dim3(NIMG * 8), dim3(256), 0, stream>>>(vws, asws, cent, out, nparts);
}